// Round 9
// baseline (25862.158 us; speedup 1.0000x reference)
//
#include <hip/hip_runtime.h>
#include <stdint.h>

#define Bv 64
#define Tv 2048
#define Iv 128
#define Hv 512
#define Ov 64

typedef _Float16 half_t;
typedef _Float16 half2_t __attribute__((ext_vector_type(2)));

__device__ __forceinline__ float fdot2(unsigned int a, unsigned int b, float c) {
#if __has_builtin(__builtin_amdgcn_fdot2)
    return __builtin_amdgcn_fdot2(__builtin_bit_cast(half2_t, a),
                                  __builtin_bit_cast(half2_t, b), c, false);
#else
    half2_t ha = __builtin_bit_cast(half2_t, a);
    half2_t hb = __builtin_bit_cast(half2_t, b);
    return c + (float)ha.x * (float)hb.x + (float)ha.y * (float)hb.y;
#endif
}

__device__ __forceinline__ unsigned int pack2(float a, float b) {
    half2_t v; v.x = (half_t)a; v.y = (half_t)b;
    return __builtin_bit_cast(unsigned int, v);
}

// ===================== FAST PATH (quad: 4 WGs per batch, 256 CUs) =====================

// wq layout [m][g][tid] (m<128, g<4, tid<256): thread (g,tid) owns output
// j = g*128 + (tid>>1), k-half s = tid&1; wq[m] = half2(wrec[j][256s+2m], +1)
__global__ void pack_wq_k(const float* __restrict__ wrec, unsigned int* __restrict__ wp) {
    int idx = blockIdx.x * 256 + threadIdx.x;            // < 131072
    if (idx >= 128 * 4 * 256) return;
    int tid = idx & 255, g = (idx >> 8) & 3, m = idx >> 10;
    int oi = tid >> 1, s = tid & 1;
    int j = g * 128 + oi;
    int k0 = 256 * s + 2 * m;
    wp[idx] = pack2(wrec[j * Hv + k0], wrec[j * Hv + k0 + 1]);
}

// wip[m][j] (m<64, j<512): half2(wi[2m][j], wi[2m+1][j])
__global__ void pack_wip_k(const float* __restrict__ wi, unsigned int* __restrict__ wp) {
    int idx = blockIdx.x * 256 + threadIdx.x;
    int j = idx & 511, m = idx >> 9;
    wp[idx] = pack2(wi[(2 * m) * Hv + j], wi[(2 * m + 1) * Hv + j]);
}

// wop4[g][o] (g<64, o<64): uint4 of half2 pairs of wout rows 8g..8g+7, col o
__global__ void pack_wop_k(const float* __restrict__ wout, uint4* __restrict__ wp) {
    int idx = blockIdx.x * 256 + threadIdx.x;
    if (idx >= 64 * 64) return;
    int o = idx & 63, g = idx >> 6;
    uint4 v;
    v.x = pack2(wout[(8 * g + 0) * Ov + o], wout[(8 * g + 1) * Ov + o]);
    v.y = pack2(wout[(8 * g + 2) * Ov + o], wout[(8 * g + 3) * Ov + o]);
    v.z = pack2(wout[(8 * g + 4) * Ov + o], wout[(8 * g + 5) * Ov + o]);
    v.w = pack2(wout[(8 * g + 6) * Ov + o], wout[(8 * g + 7) * Ov + o]);
    wp[idx] = v;
}

// z[bt][j] = 0.1 * sum_i x[bt][i]*wi[i][j] + 0.0005 * noise[bt][j], f16.
__global__ __launch_bounds__(512) void z_kernel(
    const float* __restrict__ x, const float* __restrict__ noise,
    const unsigned int* __restrict__ wip, half_t* __restrict__ zg)
{
    __shared__ uint4 xs[32 * 16];
    const int tid = threadIdx.x;
    const size_t bt0 = (size_t)blockIdx.x * 32;

    unsigned int wiR[64];
#pragma unroll
    for (int m = 0; m < 64; ++m) wiR[m] = wip[m * 512 + tid];

    for (int idx = tid; idx < 32 * 64; idx += 512) {
        int row = idx >> 6, m = idx & 63;
        float2 xv = ((const float2*)x)[(bt0 + row) * 64 + m];
        ((unsigned int*)xs)[idx] = pack2(xv.x, xv.y);
    }
    __syncthreads();

    for (int row = 0; row < 32; ++row) {
        float a0 = 0.f, a1 = 0.f, a2 = 0.f, a3 = 0.f;
#pragma unroll
        for (int g = 0; g < 16; ++g) {
            uint4 xv = xs[row * 16 + g];
            a0 = fdot2(wiR[4 * g + 0], xv.x, a0);
            a1 = fdot2(wiR[4 * g + 1], xv.y, a1);
            a2 = fdot2(wiR[4 * g + 2], xv.z, a2);
            a3 = fdot2(wiR[4 * g + 3], xv.w, a3);
        }
        float nv = noise[(bt0 + row) * 512 + tid];
        zg[(bt0 + row) * 512 + tid] = (half_t)(0.1f * ((a0 + a1) + (a2 + a3)) + 0.0005f * nv);
    }
}

// Quad scan, correctness-hardened vs R8:
//  - NO inline-asm memory ops; all data loads are compiler-managed (its waitcnts
//    stay sound regardless of spills) — R8's manual vmcnt counting was unsound.
//  - Exchange medium IS rstore (fresh row per step: no stale-cache lines possible,
//    no WAR, no double buffer).
//  - Per-batch 4 flags: writer = __syncthreads (drains stores) + release atomic
//    store; readers spin on relaxed 8B atomic loads, then one ACQUIRE atomic load
//    (emits cache invalidate) before plain uint4 reads — standard grid-sync idiom.
//  - Deadlock-safe: 256 WGs, no LDS, <=256 VGPR -> capacity >= 2 WGs/CU on 256 CUs,
//    so every WG is resident at any packing.
__global__ __launch_bounds__(256, 2) void rnn_quad(
    const unsigned int* __restrict__ wqp,    // [128][4][256]
    const half_t* __restrict__ zg,           // [B][T][512]
    const float* __restrict__ h0,
    unsigned int* flags,                     // [B][4], zeroed
    half_t* rstore)                          // [B][T][512] — scan output AND exchange
{
    const int tid = threadIdx.x;
    const int wg  = blockIdx.x;
    const int b = wg >> 2, g = wg & 3;
    const int s = tid & 1;
    const int j = g * 128 + (tid >> 1);

    // register-resident weight slice (pinned: forbid remat into the cold-cache loop)
    unsigned int wq[128];
#pragma unroll
    for (int m = 0; m < 128; ++m) wq[m] = wqp[(m * 4 + g) * 256 + tid];
#pragma unroll
    for (int m = 0; m < 128; ++m) asm volatile("" : "+v"(wq[m]));

    const unsigned int* zrow = (const unsigned int*)(zg + (size_t)b * Tv * Hv);
    const int zidx = j >> 1;                  // uint (=2 half) index in a 256-uint row
    half_t* rb = rstore + (size_t)b * Tv * Hv;
    unsigned int* flagb = flags + b * 4;

    float h = h0[j];
    {
        float rf = tanhf(h);
        float ro = __shfl_xor(rf, 2, 64);
        if ((tid & 3) == 0)
            __hip_atomic_store((unsigned int*)rb + (g * 64 + (tid >> 2)), pack2(rf, ro),
                               __ATOMIC_RELAXED, __HIP_MEMORY_SCOPE_AGENT);
        __syncthreads();                      // drains all lanes' stores (vmcnt 0)
        if (tid == 0)
            __hip_atomic_store(flagb + g, 1u, __ATOMIC_RELEASE, __HIP_MEMORY_SCOPE_AGENT);
    }

    unsigned int zcur = zrow[zidx];           // z[0] pair

    for (int t = 0; t < Tv - 1; ++t) {
        // prefetch z[t+1] (consumed next iteration -> ~a full step of slack)
        unsigned int znxt = zrow[(size_t)(t + 1) * 256 + zidx];

        const unsigned int target = (unsigned)(t + 1);
        for (;;) {
            unsigned long long f01 = __hip_atomic_load(
                (const unsigned long long*)flagb, __ATOMIC_RELAXED, __HIP_MEMORY_SCOPE_AGENT);
            unsigned long long f23 = __hip_atomic_load(
                (const unsigned long long*)(flagb + 2), __ATOMIC_RELAXED, __HIP_MEMORY_SCOPE_AGENT);
            unsigned int m0 = (unsigned)f01, m1 = (unsigned)(f01 >> 32);
            unsigned int m2 = (unsigned)f23, m3 = (unsigned)(f23 >> 32);
            if (m0 >= target && m1 >= target && m2 >= target && m3 >= target) break;
        }
        (void)__hip_atomic_load(flagb, __ATOMIC_ACQUIRE, __HIP_MEMORY_SCOPE_AGENT);  // inv

        // this thread's 512B k-half of r_t: plain loads, compiler-managed waits
        const uint4* rp = (const uint4*)((const char*)(rb + (size_t)t * Hv) + (s << 9));

        float acc0 = 0.f, acc1 = 0.f, acc2 = 0.f, acc3 = 0.f;
#pragma unroll
        for (int blk = 0; blk < 4; ++blk) {
            uint4 rv[8];
#pragma unroll
            for (int i = 0; i < 8; ++i) rv[i] = rp[blk * 8 + i];
#pragma unroll
            for (int i = 0; i < 8; ++i) {
                const int m0i = blk * 32 + 4 * i;
                acc0 = fdot2(wq[m0i + 0], rv[i].x, acc0);
                acc1 = fdot2(wq[m0i + 1], rv[i].y, acc1);
                acc2 = fdot2(wq[m0i + 2], rv[i].z, acc2);
                acc3 = fdot2(wq[m0i + 3], rv[i].w, acc3);
            }
        }

        float tot = (acc0 + acc1) + (acc2 + acc3);
        tot += __shfl_xor(tot, 1, 64);        // combine the two k-halves of this output

        half2_t zp = __builtin_bit_cast(half2_t, zcur);
        float zf = (float)((j & 1) ? zp.y : zp.x);
        h = 0.9f * h + 0.1f * tot + zf;
        float rf = tanhf(h);
        float ro = __shfl_xor(rf, 2, 64);

        if ((tid & 3) == 0)
            __hip_atomic_store(
                (unsigned int*)(rb + (size_t)(t + 1) * Hv) + (g * 64 + (tid >> 2)),
                pack2(rf, ro), __ATOMIC_RELAXED, __HIP_MEMORY_SCOPE_AGENT);
        __syncthreads();                      // all writers drained before the flag
        if (tid == 0)
            __hip_atomic_store(flagb + g, (unsigned)(t + 2),
                               __ATOMIC_RELEASE, __HIP_MEMORY_SCOPE_AGENT);

        zcur = znxt;
    }
}

// out[bt][o] = sum_j r[bt][j] * wout[j][o]
__global__ __launch_bounds__(256) void out_kernel(
    const half_t* __restrict__ rstore, const uint4* __restrict__ wop4, float* __restrict__ out)
{
    __shared__ uint4 rr[32 * 64];
    const int tid = threadIdx.x;
    const int o = tid & 63, q = tid >> 6;
    const size_t bt0 = (size_t)blockIdx.x * 32;

    for (int idx = tid; idx < 32 * 64; idx += 256)
        rr[idx] = ((const uint4*)rstore)[bt0 * 64 + idx];
    __syncthreads();

    float acc[8] = {0.f, 0.f, 0.f, 0.f, 0.f, 0.f, 0.f, 0.f};
#pragma unroll 8
    for (int g = 0; g < 64; ++g) {
        uint4 wv = wop4[g * 64 + o];
#pragma unroll
        for (int i = 0; i < 8; ++i) {
            uint4 rv = rr[(q + 4 * i) * 64 + g];
            float a = fdot2(wv.x, rv.x, acc[i]);
            a = fdot2(wv.y, rv.y, a);
            a = fdot2(wv.z, rv.z, a);
            acc[i] = fdot2(wv.w, rv.w, a);
        }
    }
#pragma unroll
    for (int i = 0; i < 8; ++i)
        out[(bt0 + q + 4 * i) * Ov + o] = acc[i];
}

// ===================== LEGACY FALLBACK (R1, proven) =====================
__global__ void pack_wrec_k(const float* __restrict__ wrec, unsigned int* __restrict__ wp) {
    int tid = blockIdx.x * 256 + threadIdx.x;
    int k = tid & 3, j = (tid >> 2) & 511, q = tid >> 11;
    int i0 = 8 * q + 2 * k;
    wp[tid] = pack2(wrec[j * Hv + i0], wrec[j * Hv + i0 + 1]);
}
__global__ void pack_wi_k(const float* __restrict__ wi, unsigned int* __restrict__ wp) {
    int tid = blockIdx.x * 256 + threadIdx.x;
    int k = tid & 3, j = (tid >> 2) & 511, q = tid >> 11;
    int i0 = 8 * q + 2 * k;
    wp[tid] = pack2(wi[i0 * Hv + j], wi[(i0 + 1) * Hv + j]);
}
__global__ void pack_wout_k(const float* __restrict__ wout, unsigned int* __restrict__ wp) {
    int tid = blockIdx.x * 256 + threadIdx.x;
    int o = tid & 63, m = tid >> 6;
    wp[tid] = pack2(wout[(2 * m) * Ov + o], wout[(2 * m + 1) * Ov + o]);
}
__global__ __launch_bounds__(512) void rnn_persistent(
    const float* __restrict__ x, const float* __restrict__ noise,
    const float* __restrict__ h0,
    const unsigned int* __restrict__ wrecp,
    const unsigned int* __restrict__ wip,
    const unsigned int* __restrict__ wop,
    float* __restrict__ out)
{
    __shared__ __align__(16) unsigned int s_r[2][256];
    __shared__ __align__(16) unsigned int s_x[64];
    const int tid = threadIdx.x;
    const int b = blockIdx.x;
    const int o = tid >> 3;
    const int g = tid & 7;
    const float* xb = x + (size_t)b * Tv * Iv;
    const float* nb = noise + (size_t)b * Tv * Hv;
    float* ob = out + (size_t)b * Tv * Ov;
    unsigned int wiReg[64];
#pragma unroll
    for (int m = 0; m < 64; ++m)
        wiReg[m] = wip[(((m >> 2) * Hv) + tid) * 4 + (m & 3)];
    unsigned int wo[32];
#pragma unroll
    for (int k = 0; k < 32; ++k)
        wo[k] = wop[(g * 32 + k) * Ov + o];
    float h = h0[tid];
    ((half_t*)&s_r[0][0])[tid] = (half_t)tanhf(h);
    __syncthreads();
    {
        float po = 0.f;
        const uint4* r2 = (const uint4*)&s_r[0][0];
#pragma unroll
        for (int k = 0; k < 8; ++k) {
            uint4 rv = r2[g * 8 + k];
            po = fdot2(wo[4 * k + 0], rv.x, po);
            po = fdot2(wo[4 * k + 1], rv.y, po);
            po = fdot2(wo[4 * k + 2], rv.z, po);
            po = fdot2(wo[4 * k + 3], rv.w, po);
        }
        po += __shfl_xor(po, 1, 64);
        po += __shfl_xor(po, 2, 64);
        po += __shfl_xor(po, 4, 64);
        if (g == 0) ob[o] = po;
    }
    const uint4* wr4 = (const uint4*)wrecp;
    int cur = 0;
    for (int t = 0; t < Tv - 1; ++t) {
        const int nxt = cur ^ 1;
        float nval = nb[t * Hv + tid];
        if (tid < Iv) ((half_t*)&s_x[0])[tid] = (half_t)xb[t * Iv + tid];
        __syncthreads();
        float acc = 0.f;
        const uint4* rr4 = (const uint4*)&s_r[cur][0];
#pragma unroll 8
        for (int q = 0; q < 64; ++q) {
            uint4 w = wr4[q * Hv + tid];
            uint4 r = rr4[q];
            acc = fdot2(w.x, r.x, acc);
            acc = fdot2(w.y, r.y, acc);
            acc = fdot2(w.z, r.z, acc);
            acc = fdot2(w.w, r.w, acc);
        }
        const uint4* xx4 = (const uint4*)&s_x[0];
#pragma unroll
        for (int m = 0; m < 16; ++m) {
            uint4 xv = xx4[m];
            acc = fdot2(wiReg[4 * m + 0], xv.x, acc);
            acc = fdot2(wiReg[4 * m + 1], xv.y, acc);
            acc = fdot2(wiReg[4 * m + 2], xv.z, acc);
            acc = fdot2(wiReg[4 * m + 3], xv.w, acc);
        }
        h = h + 0.0005f * nval + 0.1f * (acc - h);
        ((half_t*)&s_r[nxt][0])[tid] = (half_t)tanhf(h);
        __syncthreads();
        float po = 0.f;
        const uint4* r2 = (const uint4*)&s_r[nxt][0];
#pragma unroll
        for (int k = 0; k < 8; ++k) {
            uint4 rv = r2[g * 8 + k];
            po = fdot2(wo[4 * k + 0], rv.x, po);
            po = fdot2(wo[4 * k + 1], rv.y, po);
            po = fdot2(wo[4 * k + 2], rv.z, po);
            po = fdot2(wo[4 * k + 3], rv.w, po);
        }
        po += __shfl_xor(po, 1, 64);
        po += __shfl_xor(po, 2, 64);
        po += __shfl_xor(po, 4, 64);
        if (g == 0) ob[(t + 1) * Ov + o] = po;
        cur = nxt;
    }
}

// ===================== LAUNCHER =====================
extern "C" void kernel_launch(void* const* d_in, const int* in_sizes, int n_in,
                              void* d_out, int out_size, void* d_ws, size_t ws_size,
                              hipStream_t stream) {
    const float* input = (const float*)d_in[0];
    const float* noise = (const float*)d_in[1];
    const float* wi    = (const float*)d_in[2];
    const float* wrec  = (const float*)d_in[3];
    const float* wout  = (const float*)d_in[4];
    const float* h0    = (const float*)d_in[5];
    float* out = (float*)d_out;

    const size_t Z_OFF  = 0;                          // 134217728
    const size_t R_OFF  = Z_OFF + 134217728;          // 134217728
    const size_t WQ_OFF = R_OFF + 134217728;          // 524288
    const size_t WI_OFF = WQ_OFF + 524288;            // 131072
    const size_t WO_OFF = WI_OFF + 131072;            // 65536
    const size_t FL_OFF = WO_OFF + 65536;             // 4096
    const size_t NEED   = FL_OFF + 4096;              // ~256.7 MB

    if (ws_size >= NEED) {
        unsigned char* ws = (unsigned char*)d_ws;
        half_t*       zg    = (half_t*)(ws + Z_OFF);
        half_t*       rsg   = (half_t*)(ws + R_OFF);
        unsigned int* wqg   = (unsigned int*)(ws + WQ_OFF);
        unsigned int* wipg  = (unsigned int*)(ws + WI_OFF);
        uint4*        wop4g = (uint4*)(ws + WO_OFF);
        unsigned int* flg   = (unsigned int*)(ws + FL_OFF);

        hipLaunchKernelGGL(pack_wq_k,  dim3(512), dim3(256), 0, stream, wrec, wqg);
        hipLaunchKernelGGL(pack_wip_k, dim3(128), dim3(256), 0, stream, wi, wipg);
        hipLaunchKernelGGL(pack_wop_k, dim3(16),  dim3(256), 0, stream, wout, wop4g);

        hipLaunchKernelGGL(z_kernel, dim3((Bv * Tv) / 32), dim3(512), 0, stream,
                           input, noise, wipg, zg);

        (void)hipMemsetAsync(flg, 0, 4096, stream);

        hipLaunchKernelGGL(rnn_quad, dim3(Bv * 4), dim3(256), 0, stream,
                           wqg, zg, h0, flg, rsg);

        hipLaunchKernelGGL(out_kernel, dim3((Bv * Tv) / 32), dim3(256), 0, stream,
                           rsg, wop4g, out);
    } else {
        unsigned int* wrecp = (unsigned int*)d_ws;
        unsigned int* wip   = wrecp + 64 * 512 * 4;
        unsigned int* wop   = wip   + 16 * 512 * 4;
        hipLaunchKernelGGL(pack_wrec_k, dim3(512), dim3(256), 0, stream, wrec, wrecp);
        hipLaunchKernelGGL(pack_wi_k,   dim3(128), dim3(256), 0, stream, wi, wip);
        hipLaunchKernelGGL(pack_wout_k, dim3(64),  dim3(256), 0, stream, wout, wop);
        hipLaunchKernelGGL(rnn_persistent, dim3(Bv), dim3(512), 0, stream,
                           input, noise, h0, wrecp, wip, wop, out);
    }
}

// Round 10
// 3456.878 us; speedup vs baseline: 7.4814x; 7.4814x over previous
//
#include <hip/hip_runtime.h>
#include <stdint.h>

#define Bv 64
#define Tv 2048
#define Iv 128
#define Hv 512
#define Ov 64

typedef _Float16 half_t;
typedef _Float16 half2_t __attribute__((ext_vector_type(2)));

__device__ __forceinline__ float fdot2(unsigned int a, unsigned int b, float c) {
#if __has_builtin(__builtin_amdgcn_fdot2)
    return __builtin_amdgcn_fdot2(__builtin_bit_cast(half2_t, a),
                                  __builtin_bit_cast(half2_t, b), c, false);
#else
    half2_t ha = __builtin_bit_cast(half2_t, a);
    half2_t hb = __builtin_bit_cast(half2_t, b);
    return c + (float)ha.x * (float)hb.x + (float)ha.y * (float)hb.y;
#endif
}

__device__ __forceinline__ unsigned int pack2(float a, float b) {
    half2_t v; v.x = (half_t)a; v.y = (half_t)b;
    return __builtin_bit_cast(unsigned int, v);
}

// ===================== FAST PATH (S=4 k-sliced, 200/56 reg-LDS split) =====================
// Thread tid: w=tid>>6, l=tid&63, s=l>>4, u=l&15.
// Handles outputs j_p = 64w+u+16p (p<4) over k-slice [128s,128s+128).
// Per (output,slice): 64 k-pairs; m in [0,50) -> registers, m in [50,64) -> LDS.

// wrA4[row][tid], row = 50p+m (row<200): pack2(wrec[j_p][128s+2m], +1)
__global__ void pack_wrA4_k(const float* __restrict__ wrec, unsigned int* __restrict__ wp) {
    int idx = blockIdx.x * 256 + threadIdx.x;
    if (idx >= 200 * 512) return;
    int tid = idx & 511, row = idx >> 9;
    int p = row / 50, m = row % 50;
    int w = tid >> 6, lm = tid & 63, s = lm >> 4, u = lm & 15;
    int j = 64 * w + u + 16 * p;
    int k0 = 128 * s + 2 * m;
    wp[idx] = pack2(wrec[j * Hv + k0], wrec[j * Hv + k0 + 1]);
}

// wB4[g][tid][c] (g<14, c=output p): pair m=50+g of output j_c, k-slice s.
__global__ void pack_wB4_k(const float* __restrict__ wrec, unsigned int* __restrict__ wp) {
    int idx = blockIdx.x * 256 + threadIdx.x;
    if (idx >= 14 * 512 * 4) return;
    int c = idx & 3, tid = (idx >> 2) & 511, g = idx >> 11;
    int w = tid >> 6, lm = tid & 63, s = lm >> 4, u = lm & 15;
    int j = 64 * w + u + 16 * c;
    int m = 50 + g;
    int k0 = 128 * s + 2 * m;
    wp[idx] = pack2(wrec[j * Hv + k0], wrec[j * Hv + k0 + 1]);
}

// wip[m][j] (m<64, j<512): half2(wi[2m][j], wi[2m+1][j])
__global__ void pack_wip_k(const float* __restrict__ wi, unsigned int* __restrict__ wp) {
    int idx = blockIdx.x * 256 + threadIdx.x;
    int j = idx & 511, m = idx >> 9;
    wp[idx] = pack2(wi[(2 * m) * Hv + j], wi[(2 * m + 1) * Hv + j]);
}

// wop4[g][o] (g<64, o<64): uint4 of half2 pairs of wout rows 8g..8g+7, col o
__global__ void pack_wop_k(const float* __restrict__ wout, uint4* __restrict__ wp) {
    int idx = blockIdx.x * 256 + threadIdx.x;
    if (idx >= 64 * 64) return;
    int o = idx & 63, g = idx >> 6;
    uint4 v;
    v.x = pack2(wout[(8 * g + 0) * Ov + o], wout[(8 * g + 1) * Ov + o]);
    v.y = pack2(wout[(8 * g + 2) * Ov + o], wout[(8 * g + 3) * Ov + o]);
    v.z = pack2(wout[(8 * g + 4) * Ov + o], wout[(8 * g + 5) * Ov + o]);
    v.w = pack2(wout[(8 * g + 6) * Ov + o], wout[(8 * g + 7) * Ov + o]);
    wp[idx] = v;
}

// z[bt][j] = 0.1 * sum_i x[bt][i]*wi[i][j] + 0.0005 * noise[bt][j], f16.
__global__ __launch_bounds__(512) void z_kernel(
    const float* __restrict__ x, const float* __restrict__ noise,
    const unsigned int* __restrict__ wip, half_t* __restrict__ zg)
{
    __shared__ uint4 xs[32 * 16];
    const int tid = threadIdx.x;
    const size_t bt0 = (size_t)blockIdx.x * 32;

    unsigned int wiR[64];
#pragma unroll
    for (int m = 0; m < 64; ++m) wiR[m] = wip[m * 512 + tid];

    for (int idx = tid; idx < 32 * 64; idx += 512) {
        int row = idx >> 6, m = idx & 63;
        float2 xv = ((const float2*)x)[(bt0 + row) * 64 + m];
        ((unsigned int*)xs)[idx] = pack2(xv.x, xv.y);
    }
    __syncthreads();

    for (int row = 0; row < 32; ++row) {
        float a0 = 0.f, a1 = 0.f, a2 = 0.f, a3 = 0.f;
#pragma unroll
        for (int g = 0; g < 16; ++g) {
            uint4 xv = xs[row * 16 + g];
            a0 = fdot2(wiR[4 * g + 0], xv.x, a0);
            a1 = fdot2(wiR[4 * g + 1], xv.y, a1);
            a2 = fdot2(wiR[4 * g + 2], xv.z, a2);
            a3 = fdot2(wiR[4 * g + 3], xv.w, a3);
        }
        float nv = noise[(bt0 + row) * 512 + tid];
        zg[(bt0 + row) * 512 + tid] = (half_t)(0.1f * ((a0 + a1) + (a2 + a3)) + 0.0005f * nv);
    }
}

// r element j at byte: q*1088 + (j>>7)*272 + (j&127)*2   (16B skew per 128-slice)
#define RSKEW(q, j) ((q) * 1088 + ((j) >> 7) * 272 + ((j) & 127) * 2)

// 4 reg-weight dot2s against one r-uint RU at pair m=M (outputs p=0..3)
#define STEP_REG(RU, M)                                   \
    acc0 = fdot2(wrA[(M)], (RU), acc0);                   \
    acc1 = fdot2(wrA[50 + (M)], (RU), acc1);              \
    acc2 = fdot2(wrA[100 + (M)], (RU), acc2);             \
    acc3 = fdot2(wrA[150 + (M)], (RU), acc3);

// 4 LDS-weight dot2s: uint4 from wlds[(M-50)*512+tid], components = outputs
#define STEP_LDS(RU, M)                                   \
    {                                                     \
        uint4 wv = wlds[((M) - 50) * 512 + tid];          \
        acc0 = fdot2(wv.x, (RU), acc0);                   \
        acc1 = fdot2(wv.y, (RU), acc1);                   \
        acc2 = fdot2(wv.z, (RU), acc2);                   \
        acc3 = fdot2(wv.w, (RU), acc3);                   \
    }

__global__ __attribute__((amdgpu_flat_work_group_size(512, 512), amdgpu_waves_per_eu(2, 2)))
void rnn_fast(
    const unsigned int* __restrict__ wrAg,   // [200][512]
    const uint4* __restrict__ wBg,           // [14*512] uint4
    const half_t* __restrict__ zg,           // [B][T][512]
    const float* __restrict__ h0,
    half_t* __restrict__ rstore)             // [B][T][512]
{
    extern __shared__ unsigned char smem[];
    uint4* wlds = (uint4*)smem;                         // 14*512*16 = 114688 B
    unsigned char* rbase = smem + 14 * 512 * 16;        // 2*1088 = 2176 B skewed r

    const int tid = threadIdx.x;
    const int b = blockIdx.x;
    const int s = (tid >> 4) & 3;
    const int jown = ((tid >> 6) << 6) + (tid & 15) + 16 * s;   // 64w + u + 16s

    for (int i = tid; i < 14 * 512; i += 512) wlds[i] = wBg[i];

    // register weights: rows 50p+m, m in [0,50)
    unsigned int wrA[200];
#pragma unroll
    for (int m = 0; m < 200; ++m) wrA[m] = wrAg[m * 512 + tid];
    asm volatile("" ::: "memory");   // forbid remat of the weight loads inside the loop

    const half_t* zb = zg + (size_t)b * Tv * Hv;
    half_t* rb = rstore + (size_t)b * Tv * Hv;

    float h = h0[jown];
    half_t r0 = (half_t)tanhf(h);
    *(half_t*)(rbase + RSKEW(0, jown)) = r0;
    rb[jown] = r0;
    half_t zpf = zb[jown];
    __syncthreads();

    int cur = 0;
    for (int t = 0; t < Tv - 1; ++t) {
        half_t zc = zpf;
        zpf = zb[(size_t)(t + 1) * Hv + jown];

        // this thread's 128-element r-slice (16 uint4, 4-addr broadcast, bank-skewed)
        const uint4* rq = (const uint4*)(rbase + cur * 1088 + s * 272);

        float acc0 = 0.f, acc1 = 0.f, acc2 = 0.f, acc3 = 0.f;
#pragma unroll
        for (int g = 0; g < 12; ++g) {           // pairs 0..47: all-register
            uint4 rv = rq[g];
            STEP_REG(rv.x, 4 * g + 0)
            STEP_REG(rv.y, 4 * g + 1)
            STEP_REG(rv.z, 4 * g + 2)
            STEP_REG(rv.w, 4 * g + 3)
        }
        {                                        // pairs 48,49 (reg) + 50,51 (LDS)
            uint4 rv = rq[12];
            STEP_REG(rv.x, 48)
            STEP_REG(rv.y, 49)
            STEP_LDS(rv.z, 50)
            STEP_LDS(rv.w, 51)
        }
#pragma unroll
        for (int g = 13; g < 16; ++g) {          // pairs 52..63: LDS
            uint4 rv = rq[g];
            STEP_LDS(rv.x, 4 * g + 0)
            STEP_LDS(rv.y, 4 * g + 1)
            STEP_LDS(rv.z, 4 * g + 2)
            STEP_LDS(rv.w, 4 * g + 3)
        }

        // butterfly-reduce the 4 slice-partials across lane groups (xor16, xor32)
        acc0 += __shfl_xor(acc0, 16, 64); acc0 += __shfl_xor(acc0, 32, 64);
        acc1 += __shfl_xor(acc1, 16, 64); acc1 += __shfl_xor(acc1, 32, 64);
        acc2 += __shfl_xor(acc2, 16, 64); acc2 += __shfl_xor(acc2, 32, 64);
        acc3 += __shfl_xor(acc3, 16, 64); acc3 += __shfl_xor(acc3, 32, 64);

        // this lane owns output p = s
        float t01 = (s & 1) ? acc1 : acc0;
        float t23 = (s & 1) ? acc3 : acc2;
        float tot = (s & 2) ? t23 : t01;

        h = 0.9f * h + 0.1f * tot + (float)zc;
        half_t r = (half_t)tanhf(h);
        *(half_t*)(rbase + RSKEW(cur ^ 1, jown)) = r;
        rb[(size_t)(t + 1) * Hv + jown] = r;
        __syncthreads();
        cur ^= 1;
    }
}

// out[bt][o] = sum_j r[bt][j] * wout[j][o]
__global__ __launch_bounds__(256) void out_kernel(
    const half_t* __restrict__ rstore, const uint4* __restrict__ wop4, float* __restrict__ out)
{
    __shared__ uint4 rr[32 * 64];
    const int tid = threadIdx.x;
    const int o = tid & 63, q = tid >> 6;
    const size_t bt0 = (size_t)blockIdx.x * 32;

    for (int idx = tid; idx < 32 * 64; idx += 256)
        rr[idx] = ((const uint4*)rstore)[bt0 * 64 + idx];
    __syncthreads();

    float acc[8] = {0.f, 0.f, 0.f, 0.f, 0.f, 0.f, 0.f, 0.f};
#pragma unroll 8
    for (int g = 0; g < 64; ++g) {
        uint4 wv = wop4[g * 64 + o];
#pragma unroll
        for (int i = 0; i < 8; ++i) {
            uint4 rv = rr[(q + 4 * i) * 64 + g];
            float a = fdot2(wv.x, rv.x, acc[i]);
            a = fdot2(wv.y, rv.y, a);
            a = fdot2(wv.z, rv.z, a);
            acc[i] = fdot2(wv.w, rv.w, a);
        }
    }
#pragma unroll
    for (int i = 0; i < 8; ++i)
        out[(bt0 + q + 4 * i) * Ov + o] = acc[i];
}

// ===================== LEGACY FALLBACK (R1, proven) =====================
__global__ void pack_wrec_k(const float* __restrict__ wrec, unsigned int* __restrict__ wp) {
    int tid = blockIdx.x * 256 + threadIdx.x;
    int k = tid & 3, j = (tid >> 2) & 511, q = tid >> 11;
    int i0 = 8 * q + 2 * k;
    wp[tid] = pack2(wrec[j * Hv + i0], wrec[j * Hv + i0 + 1]);
}
__global__ void pack_wi_k(const float* __restrict__ wi, unsigned int* __restrict__ wp) {
    int tid = blockIdx.x * 256 + threadIdx.x;
    int k = tid & 3, j = (tid >> 2) & 511, q = tid >> 11;
    int i0 = 8 * q + 2 * k;
    wp[tid] = pack2(wi[i0 * Hv + j], wi[(i0 + 1) * Hv + j]);
}
__global__ void pack_wout_k(const float* __restrict__ wout, unsigned int* __restrict__ wp) {
    int tid = blockIdx.x * 256 + threadIdx.x;
    int o = tid & 63, m = tid >> 6;
    wp[tid] = pack2(wout[(2 * m) * Ov + o], wout[(2 * m + 1) * Ov + o]);
}
__global__ __launch_bounds__(512) void rnn_persistent(
    const float* __restrict__ x, const float* __restrict__ noise,
    const float* __restrict__ h0,
    const unsigned int* __restrict__ wrecp,
    const unsigned int* __restrict__ wip,
    const unsigned int* __restrict__ wop,
    float* __restrict__ out)
{
    __shared__ __align__(16) unsigned int s_r[2][256];
    __shared__ __align__(16) unsigned int s_x[64];
    const int tid = threadIdx.x;
    const int b = blockIdx.x;
    const int o = tid >> 3;
    const int g = tid & 7;
    const float* xb = x + (size_t)b * Tv * Iv;
    const float* nb = noise + (size_t)b * Tv * Hv;
    float* ob = out + (size_t)b * Tv * Ov;
    unsigned int wiReg[64];
#pragma unroll
    for (int m = 0; m < 64; ++m)
        wiReg[m] = wip[(((m >> 2) * Hv) + tid) * 4 + (m & 3)];
    unsigned int wo[32];
#pragma unroll
    for (int k = 0; k < 32; ++k)
        wo[k] = wop[(g * 32 + k) * Ov + o];
    float h = h0[tid];
    ((half_t*)&s_r[0][0])[tid] = (half_t)tanhf(h);
    __syncthreads();
    {
        float po = 0.f;
        const uint4* r2 = (const uint4*)&s_r[0][0];
#pragma unroll
        for (int k = 0; k < 8; ++k) {
            uint4 rv = r2[g * 8 + k];
            po = fdot2(wo[4 * k + 0], rv.x, po);
            po = fdot2(wo[4 * k + 1], rv.y, po);
            po = fdot2(wo[4 * k + 2], rv.z, po);
            po = fdot2(wo[4 * k + 3], rv.w, po);
        }
        po += __shfl_xor(po, 1, 64);
        po += __shfl_xor(po, 2, 64);
        po += __shfl_xor(po, 4, 64);
        if (g == 0) ob[o] = po;
    }
    const uint4* wr4 = (const uint4*)wrecp;
    int cur = 0;
    for (int t = 0; t < Tv - 1; ++t) {
        const int nxt = cur ^ 1;
        float nval = nb[t * Hv + tid];
        if (tid < Iv) ((half_t*)&s_x[0])[tid] = (half_t)xb[t * Iv + tid];
        __syncthreads();
        float acc = 0.f;
        const uint4* rr4 = (const uint4*)&s_r[cur][0];
#pragma unroll 8
        for (int q = 0; q < 64; ++q) {
            uint4 w = wr4[q * Hv + tid];
            uint4 r = rr4[q];
            acc = fdot2(w.x, r.x, acc);
            acc = fdot2(w.y, r.y, acc);
            acc = fdot2(w.z, r.z, acc);
            acc = fdot2(w.w, r.w, acc);
        }
        const uint4* xx4 = (const uint4*)&s_x[0];
#pragma unroll
        for (int m = 0; m < 16; ++m) {
            uint4 xv = xx4[m];
            acc = fdot2(wiReg[4 * m + 0], xv.x, acc);
            acc = fdot2(wiReg[4 * m + 1], xv.y, acc);
            acc = fdot2(wiReg[4 * m + 2], xv.z, acc);
            acc = fdot2(wiReg[4 * m + 3], xv.w, acc);
        }
        h = h + 0.0005f * nval + 0.1f * (acc - h);
        ((half_t*)&s_r[nxt][0])[tid] = (half_t)tanhf(h);
        __syncthreads();
        float po = 0.f;
        const uint4* r2 = (const uint4*)&s_r[nxt][0];
#pragma unroll
        for (int k = 0; k < 8; ++k) {
            uint4 rv = r2[g * 8 + k];
            po = fdot2(wo[4 * k + 0], rv.x, po);
            po = fdot2(wo[4 * k + 1], rv.y, po);
            po = fdot2(wo[4 * k + 2], rv.z, po);
            po = fdot2(wo[4 * k + 3], rv.w, po);
        }
        po += __shfl_xor(po, 1, 64);
        po += __shfl_xor(po, 2, 64);
        po += __shfl_xor(po, 4, 64);
        if (g == 0) ob[(t + 1) * Ov + o] = po;
        cur = nxt;
    }
}

// ===================== LAUNCHER =====================
extern "C" void kernel_launch(void* const* d_in, const int* in_sizes, int n_in,
                              void* d_out, int out_size, void* d_ws, size_t ws_size,
                              hipStream_t stream) {
    const float* input = (const float*)d_in[0];
    const float* noise = (const float*)d_in[1];
    const float* wi    = (const float*)d_in[2];
    const float* wrec  = (const float*)d_in[3];
    const float* wout  = (const float*)d_in[4];
    const float* h0    = (const float*)d_in[5];
    float* out = (float*)d_out;

    const size_t Z_OFF  = 0;
    const size_t R_OFF  = Z_OFF + 134217728;
    const size_t WA_OFF = R_OFF + 134217728;          // wrA: 200*512*4 = 409600
    const size_t WB_OFF = WA_OFF + 409600;            // wB:  14*512*16 = 114688
    const size_t WI_OFF = WB_OFF + 114688;            // wip: 131072
    const size_t WO_OFF = WI_OFF + 131072;            // wop4: 65536
    const size_t NEED   = WO_OFF + 65536;

    if (ws_size >= NEED) {
        unsigned char* ws = (unsigned char*)d_ws;
        half_t*       zg    = (half_t*)(ws + Z_OFF);
        half_t*       rsg   = (half_t*)(ws + R_OFF);
        unsigned int* wrAg  = (unsigned int*)(ws + WA_OFF);
        unsigned int* wBg   = (unsigned int*)(ws + WB_OFF);
        unsigned int* wipg  = (unsigned int*)(ws + WI_OFF);
        uint4*        wop4g = (uint4*)(ws + WO_OFF);

        hipLaunchKernelGGL(pack_wrA4_k, dim3(400), dim3(256), 0, stream, wrec, wrAg);
        hipLaunchKernelGGL(pack_wB4_k,  dim3(112), dim3(256), 0, stream, wrec, wBg);
        hipLaunchKernelGGL(pack_wip_k,  dim3(128), dim3(256), 0, stream, wi, wipg);
        hipLaunchKernelGGL(pack_wop_k,  dim3(16),  dim3(256), 0, stream, wout, wop4g);

        hipLaunchKernelGGL(z_kernel, dim3((Bv * Tv) / 32), dim3(512), 0, stream,
                           input, noise, wipg, zg);

        const int smem = 14 * 512 * 16 + 2 * 1088;   // 116864 B
        hipFuncSetAttribute((const void*)rnn_fast,
                            hipFuncAttributeMaxDynamicSharedMemorySize, smem);
        hipLaunchKernelGGL(rnn_fast, dim3(Bv), dim3(512), smem, stream,
                           wrAg, (const uint4*)wBg, zg, h0, rsg);

        hipLaunchKernelGGL(out_kernel, dim3((Bv * Tv) / 32), dim3(256), 0, stream,
                           rsg, wop4g, out);
    } else {
        unsigned int* wrecp = (unsigned int*)d_ws;
        unsigned int* wip   = wrecp + 64 * 512 * 4;
        unsigned int* wop   = wip   + 16 * 512 * 4;
        hipLaunchKernelGGL(pack_wrec_k, dim3(512), dim3(256), 0, stream, wrec, wrecp);
        hipLaunchKernelGGL(pack_wi_k,   dim3(128), dim3(256), 0, stream, wi, wip);
        hipLaunchKernelGGL(pack_wout_k, dim3(64),  dim3(256), 0, stream, wout, wop);
        hipLaunchKernelGGL(rnn_persistent, dim3(Bv), dim3(512), 0, stream,
                           input, noise, h0, wrecp, wip, wop, out);
    }
}

// Round 11
// 3437.462 us; speedup vs baseline: 7.5236x; 1.0056x over previous
//
#include <hip/hip_runtime.h>
#include <stdint.h>

#define Bv 64
#define Tv 2048
#define Iv 128
#define Hv 512
#define Ov 64

typedef _Float16 half_t;
typedef _Float16 half2_t __attribute__((ext_vector_type(2)));

__device__ __forceinline__ float fdot2(unsigned int a, unsigned int b, float c) {
#if __has_builtin(__builtin_amdgcn_fdot2)
    return __builtin_amdgcn_fdot2(__builtin_bit_cast(half2_t, a),
                                  __builtin_bit_cast(half2_t, b), c, false);
#else
    half2_t ha = __builtin_bit_cast(half2_t, a);
    half2_t hb = __builtin_bit_cast(half2_t, b);
    return c + (float)ha.x * (float)hb.x + (float)ha.y * (float)hb.y;
#endif
}

__device__ __forceinline__ unsigned int pack2(float a, float b) {
    half2_t v; v.x = (half_t)a; v.y = (half_t)b;
    return __builtin_bit_cast(unsigned int, v);
}

// ===================== FAST PATH (S=4 k-sliced, 200/56 reg-LDS split) =====================
// Thread tid: w=tid>>6, l=tid&63, s=l>>4, u=l&15.
// Handles outputs j_p = 64w+u+16p (p<4) over k-slice [128s,128s+128).
// Per (output,slice): 64 k-pairs; m in [0,50) -> registers, m in [50,64) -> LDS.

// wrA4[row][tid], row = 50p+m (row<200): pack2(wrec[j_p][128s+2m], +1)
__global__ void pack_wrA4_k(const float* __restrict__ wrec, unsigned int* __restrict__ wp) {
    int idx = blockIdx.x * 256 + threadIdx.x;
    if (idx >= 200 * 512) return;
    int tid = idx & 511, row = idx >> 9;
    int p = row / 50, m = row % 50;
    int w = tid >> 6, lm = tid & 63, s = lm >> 4, u = lm & 15;
    int j = 64 * w + u + 16 * p;
    int k0 = 128 * s + 2 * m;
    wp[idx] = pack2(wrec[j * Hv + k0], wrec[j * Hv + k0 + 1]);
}

// wB4[g][tid][c] (g<14, c=output p): pair m=50+g of output j_c, k-slice s.
__global__ void pack_wB4_k(const float* __restrict__ wrec, unsigned int* __restrict__ wp) {
    int idx = blockIdx.x * 256 + threadIdx.x;
    if (idx >= 14 * 512 * 4) return;
    int c = idx & 3, tid = (idx >> 2) & 511, g = idx >> 11;
    int w = tid >> 6, lm = tid & 63, s = lm >> 4, u = lm & 15;
    int j = 64 * w + u + 16 * c;
    int m = 50 + g;
    int k0 = 128 * s + 2 * m;
    wp[idx] = pack2(wrec[j * Hv + k0], wrec[j * Hv + k0 + 1]);
}

// wip[m][j] (m<64, j<512): half2(wi[2m][j], wi[2m+1][j])
__global__ void pack_wip_k(const float* __restrict__ wi, unsigned int* __restrict__ wp) {
    int idx = blockIdx.x * 256 + threadIdx.x;
    int j = idx & 511, m = idx >> 9;
    wp[idx] = pack2(wi[(2 * m) * Hv + j], wi[(2 * m + 1) * Hv + j]);
}

// wop4[g][o] (g<64, o<64): uint4 of half2 pairs of wout rows 8g..8g+7, col o
__global__ void pack_wop_k(const float* __restrict__ wout, uint4* __restrict__ wp) {
    int idx = blockIdx.x * 256 + threadIdx.x;
    if (idx >= 64 * 64) return;
    int o = idx & 63, g = idx >> 6;
    uint4 v;
    v.x = pack2(wout[(8 * g + 0) * Ov + o], wout[(8 * g + 1) * Ov + o]);
    v.y = pack2(wout[(8 * g + 2) * Ov + o], wout[(8 * g + 3) * Ov + o]);
    v.z = pack2(wout[(8 * g + 4) * Ov + o], wout[(8 * g + 5) * Ov + o]);
    v.w = pack2(wout[(8 * g + 6) * Ov + o], wout[(8 * g + 7) * Ov + o]);
    wp[idx] = v;
}

// z[bt][j] = 0.1 * sum_i x[bt][i]*wi[i][j] + 0.0005 * noise[bt][j], f16.
__global__ __launch_bounds__(512) void z_kernel(
    const float* __restrict__ x, const float* __restrict__ noise,
    const unsigned int* __restrict__ wip, half_t* __restrict__ zg)
{
    __shared__ uint4 xs[32 * 16];
    const int tid = threadIdx.x;
    const size_t bt0 = (size_t)blockIdx.x * 32;

    unsigned int wiR[64];
#pragma unroll
    for (int m = 0; m < 64; ++m) wiR[m] = wip[m * 512 + tid];

    for (int idx = tid; idx < 32 * 64; idx += 512) {
        int row = idx >> 6, m = idx & 63;
        float2 xv = ((const float2*)x)[(bt0 + row) * 64 + m];
        ((unsigned int*)xs)[idx] = pack2(xv.x, xv.y);
    }
    __syncthreads();

    for (int row = 0; row < 32; ++row) {
        float a0 = 0.f, a1 = 0.f, a2 = 0.f, a3 = 0.f;
#pragma unroll
        for (int g = 0; g < 16; ++g) {
            uint4 xv = xs[row * 16 + g];
            a0 = fdot2(wiR[4 * g + 0], xv.x, a0);
            a1 = fdot2(wiR[4 * g + 1], xv.y, a1);
            a2 = fdot2(wiR[4 * g + 2], xv.z, a2);
            a3 = fdot2(wiR[4 * g + 3], xv.w, a3);
        }
        float nv = noise[(bt0 + row) * 512 + tid];
        zg[(bt0 + row) * 512 + tid] = (half_t)(0.1f * ((a0 + a1) + (a2 + a3)) + 0.0005f * nv);
    }
}

// r element j at byte: q*1088 + (j>>7)*272 + (j&127)*2   (16B skew per 128-slice)
#define RSKEW(q, j) ((q) * 1088 + ((j) >> 7) * 272 + ((j) & 127) * 2)

// 4 reg-weight dot2s against one r-uint RU at pair m=M (outputs p=0..3)
#define STEP_REG(RU, M)                                   \
    acc0 = fdot2(wrA[(M)], (RU), acc0);                   \
    acc1 = fdot2(wrA[50 + (M)], (RU), acc1);              \
    acc2 = fdot2(wrA[100 + (M)], (RU), acc2);             \
    acc3 = fdot2(wrA[150 + (M)], (RU), acc3);

// 4 LDS-weight dot2s: uint4 from wlds[(M-50)*512+tid], components = outputs
#define STEP_LDS(RU, M)                                   \
    {                                                     \
        uint4 wv = wlds[((M) - 50) * 512 + tid];          \
        acc0 = fdot2(wv.x, (RU), acc0);                   \
        acc1 = fdot2(wv.y, (RU), acc1);                   \
        acc2 = fdot2(wv.z, (RU), acc2);                   \
        acc3 = fdot2(wv.w, (RU), acc3);                   \
    }

// R11 change vs R10 (single variable): the rstore global write is moved to the
// TOP of the next iteration. __syncthreads drains vmcnt(0) (guide-verified), so a
// store issued just before the barrier puts its full ack latency on the critical
// path every step. Issued after the barrier instead, it has a whole step to retire.
__global__ __attribute__((amdgpu_flat_work_group_size(512, 512), amdgpu_waves_per_eu(2, 2)))
void rnn_fast(
    const unsigned int* __restrict__ wrAg,   // [200][512]
    const uint4* __restrict__ wBg,           // [14*512] uint4
    const half_t* __restrict__ zg,           // [B][T][512]
    const float* __restrict__ h0,
    half_t* __restrict__ rstore)             // [B][T][512]
{
    extern __shared__ unsigned char smem[];
    uint4* wlds = (uint4*)smem;                         // 14*512*16 = 114688 B
    unsigned char* rbase = smem + 14 * 512 * 16;        // 2*1088 = 2176 B skewed r

    const int tid = threadIdx.x;
    const int b = blockIdx.x;
    const int s = (tid >> 4) & 3;
    const int jown = ((tid >> 6) << 6) + (tid & 15) + 16 * s;   // 64w + u + 16s

    for (int i = tid; i < 14 * 512; i += 512) wlds[i] = wBg[i];

    // register weights: rows 50p+m, m in [0,50)
    unsigned int wrA[200];
#pragma unroll
    for (int m = 0; m < 200; ++m) wrA[m] = wrAg[m * 512 + tid];
    asm volatile("" ::: "memory");   // forbid remat of the weight loads inside the loop

    const half_t* zb = zg + (size_t)b * Tv * Hv;
    half_t* rb = rstore + (size_t)b * Tv * Hv;

    float h = h0[jown];
    half_t rhold = (half_t)tanhf(h);          // r_0, stored at loop top of t=0
    *(half_t*)(rbase + RSKEW(0, jown)) = rhold;
    half_t zpf = zb[jown];
    __syncthreads();

    int cur = 0;
    for (int t = 0; t < Tv - 1; ++t) {
        half_t zc = zpf;
        zpf = zb[(size_t)(t + 1) * Hv + jown];

        // store r_t now (just after the barrier): a full step to retire before
        // the next vmcnt(0) drain, instead of stalling the barrier.
        rb[(size_t)t * Hv + jown] = rhold;

        // this thread's 128-element r-slice (16 uint4, 4-addr broadcast, bank-skewed)
        const uint4* rq = (const uint4*)(rbase + cur * 1088 + s * 272);

        float acc0 = 0.f, acc1 = 0.f, acc2 = 0.f, acc3 = 0.f;
#pragma unroll
        for (int g = 0; g < 12; ++g) {           // pairs 0..47: all-register
            uint4 rv = rq[g];
            STEP_REG(rv.x, 4 * g + 0)
            STEP_REG(rv.y, 4 * g + 1)
            STEP_REG(rv.z, 4 * g + 2)
            STEP_REG(rv.w, 4 * g + 3)
        }
        {                                        // pairs 48,49 (reg) + 50,51 (LDS)
            uint4 rv = rq[12];
            STEP_REG(rv.x, 48)
            STEP_REG(rv.y, 49)
            STEP_LDS(rv.z, 50)
            STEP_LDS(rv.w, 51)
        }
#pragma unroll
        for (int g = 13; g < 16; ++g) {          // pairs 52..63: LDS
            uint4 rv = rq[g];
            STEP_LDS(rv.x, 4 * g + 0)
            STEP_LDS(rv.y, 4 * g + 1)
            STEP_LDS(rv.z, 4 * g + 2)
            STEP_LDS(rv.w, 4 * g + 3)
        }

        // butterfly-reduce the 4 slice-partials across lane groups (xor16, xor32)
        acc0 += __shfl_xor(acc0, 16, 64); acc0 += __shfl_xor(acc0, 32, 64);
        acc1 += __shfl_xor(acc1, 16, 64); acc1 += __shfl_xor(acc1, 32, 64);
        acc2 += __shfl_xor(acc2, 16, 64); acc2 += __shfl_xor(acc2, 32, 64);
        acc3 += __shfl_xor(acc3, 16, 64); acc3 += __shfl_xor(acc3, 32, 64);

        // this lane owns output p = s
        float t01 = (s & 1) ? acc1 : acc0;
        float t23 = (s & 1) ? acc3 : acc2;
        float tot = (s & 2) ? t23 : t01;

        h = 0.9f * h + 0.1f * tot + (float)zc;
        half_t r = (half_t)tanhf(h);
        *(half_t*)(rbase + RSKEW(cur ^ 1, jown)) = r;
        rhold = r;                                // global store deferred to next top
        __syncthreads();
        cur ^= 1;
    }
    // final row: r_{Tv-1}
    rb[(size_t)(Tv - 1) * Hv + jown] = rhold;
}

// out[bt][o] = sum_j r[bt][j] * wout[j][o]
__global__ __launch_bounds__(256) void out_kernel(
    const half_t* __restrict__ rstore, const uint4* __restrict__ wop4, float* __restrict__ out)
{
    __shared__ uint4 rr[32 * 64];
    const int tid = threadIdx.x;
    const int o = tid & 63, q = tid >> 6;
    const size_t bt0 = (size_t)blockIdx.x * 32;

    for (int idx = tid; idx < 32 * 64; idx += 256)
        rr[idx] = ((const uint4*)rstore)[bt0 * 64 + idx];
    __syncthreads();

    float acc[8] = {0.f, 0.f, 0.f, 0.f, 0.f, 0.f, 0.f, 0.f};
#pragma unroll 8
    for (int g = 0; g < 64; ++g) {
        uint4 wv = wop4[g * 64 + o];
#pragma unroll
        for (int i = 0; i < 8; ++i) {
            uint4 rv = rr[(q + 4 * i) * 64 + g];
            float a = fdot2(wv.x, rv.x, acc[i]);
            a = fdot2(wv.y, rv.y, a);
            a = fdot2(wv.z, rv.z, a);
            acc[i] = fdot2(wv.w, rv.w, a);
        }
    }
#pragma unroll
    for (int i = 0; i < 8; ++i)
        out[(bt0 + q + 4 * i) * Ov + o] = acc[i];
}

// ===================== LEGACY FALLBACK (R1, proven) =====================
__global__ void pack_wrec_k(const float* __restrict__ wrec, unsigned int* __restrict__ wp) {
    int tid = blockIdx.x * 256 + threadIdx.x;
    int k = tid & 3, j = (tid >> 2) & 511, q = tid >> 11;
    int i0 = 8 * q + 2 * k;
    wp[tid] = pack2(wrec[j * Hv + i0], wrec[j * Hv + i0 + 1]);
}
__global__ void pack_wi_k(const float* __restrict__ wi, unsigned int* __restrict__ wp) {
    int tid = blockIdx.x * 256 + threadIdx.x;
    int k = tid & 3, j = (tid >> 2) & 511, q = tid >> 11;
    int i0 = 8 * q + 2 * k;
    wp[tid] = pack2(wi[i0 * Hv + j], wi[(i0 + 1) * Hv + j]);
}
__global__ void pack_wout_k(const float* __restrict__ wout, unsigned int* __restrict__ wp) {
    int tid = blockIdx.x * 256 + threadIdx.x;
    int o = tid & 63, m = tid >> 6;
    wp[tid] = pack2(wout[(2 * m) * Ov + o], wout[(2 * m + 1) * Ov + o]);
}
__global__ __launch_bounds__(512) void rnn_persistent(
    const float* __restrict__ x, const float* __restrict__ noise,
    const float* __restrict__ h0,
    const unsigned int* __restrict__ wrecp,
    const unsigned int* __restrict__ wip,
    const unsigned int* __restrict__ wop,
    float* __restrict__ out)
{
    __shared__ __align__(16) unsigned int s_r[2][256];
    __shared__ __align__(16) unsigned int s_x[64];
    const int tid = threadIdx.x;
    const int b = blockIdx.x;
    const int o = tid >> 3;
    const int g = tid & 7;
    const float* xb = x + (size_t)b * Tv * Iv;
    const float* nb = noise + (size_t)b * Tv * Hv;
    float* ob = out + (size_t)b * Tv * Ov;
    unsigned int wiReg[64];
#pragma unroll
    for (int m = 0; m < 64; ++m)
        wiReg[m] = wip[(((m >> 2) * Hv) + tid) * 4 + (m & 3)];
    unsigned int wo[32];
#pragma unroll
    for (int k = 0; k < 32; ++k)
        wo[k] = wop[(g * 32 + k) * Ov + o];
    float h = h0[tid];
    ((half_t*)&s_r[0][0])[tid] = (half_t)tanhf(h);
    __syncthreads();
    {
        float po = 0.f;
        const uint4* r2 = (const uint4*)&s_r[0][0];
#pragma unroll
        for (int k = 0; k < 8; ++k) {
            uint4 rv = r2[g * 8 + k];
            po = fdot2(wo[4 * k + 0], rv.x, po);
            po = fdot2(wo[4 * k + 1], rv.y, po);
            po = fdot2(wo[4 * k + 2], rv.z, po);
            po = fdot2(wo[4 * k + 3], rv.w, po);
        }
        po += __shfl_xor(po, 1, 64);
        po += __shfl_xor(po, 2, 64);
        po += __shfl_xor(po, 4, 64);
        if (g == 0) ob[o] = po;
    }
    const uint4* wr4 = (const uint4*)wrecp;
    int cur = 0;
    for (int t = 0; t < Tv - 1; ++t) {
        const int nxt = cur ^ 1;
        float nval = nb[t * Hv + tid];
        if (tid < Iv) ((half_t*)&s_x[0])[tid] = (half_t)xb[t * Iv + tid];
        __syncthreads();
        float acc = 0.f;
        const uint4* rr4 = (const uint4*)&s_r[cur][0];
#pragma unroll 8
        for (int q = 0; q < 64; ++q) {
            uint4 w = wr4[q * Hv + tid];
            uint4 r = rr4[q];
            acc = fdot2(w.x, r.x, acc);
            acc = fdot2(w.y, r.y, acc);
            acc = fdot2(w.z, r.z, acc);
            acc = fdot2(w.w, r.w, acc);
        }
        const uint4* xx4 = (const uint4*)&s_x[0];
#pragma unroll
        for (int m = 0; m < 16; ++m) {
            uint4 xv = xx4[m];
            acc = fdot2(wiReg[4 * m + 0], xv.x, acc);
            acc = fdot2(wiReg[4 * m + 1], xv.y, acc);
            acc = fdot2(wiReg[4 * m + 2], xv.z, acc);
            acc = fdot2(wiReg[4 * m + 3], xv.w, acc);
        }
        h = h + 0.0005f * nval + 0.1f * (acc - h);
        ((half_t*)&s_r[nxt][0])[tid] = (half_t)tanhf(h);
        __syncthreads();
        float po = 0.f;
        const uint4* r2 = (const uint4*)&s_r[nxt][0];
#pragma unroll
        for (int k = 0; k < 8; ++k) {
            uint4 rv = r2[g * 8 + k];
            po = fdot2(wo[4 * k + 0], rv.x, po);
            po = fdot2(wo[4 * k + 1], rv.y, po);
            po = fdot2(wo[4 * k + 2], rv.z, po);
            po = fdot2(wo[4 * k + 3], rv.w, po);
        }
        po += __shfl_xor(po, 1, 64);
        po += __shfl_xor(po, 2, 64);
        po += __shfl_xor(po, 4, 64);
        if (g == 0) ob[(t + 1) * Ov + o] = po;
        cur = nxt;
    }
}

// ===================== LAUNCHER =====================
extern "C" void kernel_launch(void* const* d_in, const int* in_sizes, int n_in,
                              void* d_out, int out_size, void* d_ws, size_t ws_size,
                              hipStream_t stream) {
    const float* input = (const float*)d_in[0];
    const float* noise = (const float*)d_in[1];
    const float* wi    = (const float*)d_in[2];
    const float* wrec  = (const float*)d_in[3];
    const float* wout  = (const float*)d_in[4];
    const float* h0    = (const float*)d_in[5];
    float* out = (float*)d_out;

    const size_t Z_OFF  = 0;
    const size_t R_OFF  = Z_OFF + 134217728;
    const size_t WA_OFF = R_OFF + 134217728;          // wrA: 200*512*4 = 409600
    const size_t WB_OFF = WA_OFF + 409600;            // wB:  14*512*16 = 114688
    const size_t WI_OFF = WB_OFF + 114688;            // wip: 131072
    const size_t WO_OFF = WI_OFF + 131072;            // wop4: 65536
    const size_t NEED   = WO_OFF + 65536;

    if (ws_size >= NEED) {
        unsigned char* ws = (unsigned char*)d_ws;
        half_t*       zg    = (half_t*)(ws + Z_OFF);
        half_t*       rsg   = (half_t*)(ws + R_OFF);
        unsigned int* wrAg  = (unsigned int*)(ws + WA_OFF);
        unsigned int* wBg   = (unsigned int*)(ws + WB_OFF);
        unsigned int* wipg  = (unsigned int*)(ws + WI_OFF);
        uint4*        wop4g = (uint4*)(ws + WO_OFF);

        hipLaunchKernelGGL(pack_wrA4_k, dim3(400), dim3(256), 0, stream, wrec, wrAg);
        hipLaunchKernelGGL(pack_wB4_k,  dim3(112), dim3(256), 0, stream, wrec, wBg);
        hipLaunchKernelGGL(pack_wip_k,  dim3(128), dim3(256), 0, stream, wi, wipg);
        hipLaunchKernelGGL(pack_wop_k,  dim3(16),  dim3(256), 0, stream, wout, wop4g);

        hipLaunchKernelGGL(z_kernel, dim3((Bv * Tv) / 32), dim3(512), 0, stream,
                           input, noise, wipg, zg);

        const int smem = 14 * 512 * 16 + 2 * 1088;   // 116864 B
        hipFuncSetAttribute((const void*)rnn_fast,
                            hipFuncAttributeMaxDynamicSharedMemorySize, smem);
        hipLaunchKernelGGL(rnn_fast, dim3(Bv), dim3(512), smem, stream,
                           wrAg, (const uint4*)wBg, zg, h0, rsg);

        hipLaunchKernelGGL(out_kernel, dim3((Bv * Tv) / 32), dim3(256), 0, stream,
                           rsg, wop4g, out);
    } else {
        unsigned int* wrecp = (unsigned int*)d_ws;
        unsigned int* wip   = wrecp + 64 * 512 * 4;
        unsigned int* wop   = wip   + 16 * 512 * 4;
        hipLaunchKernelGGL(pack_wrec_k, dim3(512), dim3(256), 0, stream, wrec, wrecp);
        hipLaunchKernelGGL(pack_wi_k,   dim3(128), dim3(256), 0, stream, wi, wip);
        hipLaunchKernelGGL(pack_wout_k, dim3(64),  dim3(256), 0, stream, wout, wop);
        hipLaunchKernelGGL(rnn_persistent, dim3(Bv), dim3(512), 0, stream,
                           input, noise, h0, wrecp, wip, wop, out);
    }
}